// Round 6
// baseline (222.297 us; speedup 1.0000x reference)
//
#include <hip/hip_runtime.h>

typedef unsigned short ushort_t;

#define M_DIM 1024   // 2*512 rows of x
#define N_DIM 4096   // OUT_F
#define K_DIM 4096   // IN_F
#define NFREQ 10000
constexpr float SCALE = 150.0f / 64.0f;   // 150 / sqrt(4096)

typedef __bf16 bf16x8_t  __attribute__((ext_vector_type(8)));
typedef float  f32x16_t  __attribute__((ext_vector_type(16)));

// Native RNE f32->bf16 (R4: measured -2us steady vs bit-twiddle RNE)
__device__ inline ushort_t f2bf(float f) {
  union { __bf16 h; ushort_t u; } v;
  v.h = (__bf16)f;
  return v.u;
}

// ---------------------------------------------------------------------------
// Kernel 1: W' = bf16( weight + s * iwht(scatter(spectrum,idx)) ), plus
// x fp32->bf16 folded in as grid-y slice 0. Structure = R4 best-known
// (~50us steady). Ledger: phases1-3 ~5us (R1); ILP prefetch hurts via
// occupancy (R2); 2x slices hurt via redundancy (R3); native cvt -2us (R4).
// R6 addition: the cvt slice's block 0 also zeroes the split-K ticket/ready
// flags (stream-ordered before gemm).
// ---------------------------------------------------------------------------
__global__ __launch_bounds__(256) void build_w4(
    const float* __restrict__ weight,
    const float* __restrict__ spectrum,
    const int* __restrict__ idx,          // [2][NFREQ]: row 0 = r (out), row 1 = c (in)
    const float* __restrict__ x,
    ushort_t* __restrict__ wb,
    ushort_t* __restrict__ xb,
    int* __restrict__ tickets,            // [256]
    int* __restrict__ ready) {            // [256]
  // ---- folded cvt_x slice (dispatched first) ----
  if (blockIdx.y == 0) {
    int flat = blockIdx.x * 256 + threadIdx.x;    // 16384 threads
    if (blockIdx.x == 0) {                        // zero split-K flags
      __hip_atomic_store(&tickets[threadIdx.x], 0,
                         __ATOMIC_RELAXED, __HIP_MEMORY_SCOPE_AGENT);
      __hip_atomic_store(&ready[threadIdx.x], 0,
                         __ATOMIC_RELAXED, __HIP_MEMORY_SCOPE_AGENT);
    }
#pragma unroll 4
    for (int k = 0; k < 64; ++k) {
      int i = flat + k * 16384;                   // M*K/4 = 1048576 float4s
      float4 v = ((const float4*)x)[i];
      ushort4 o;
      o.x = f2bf(v.x); o.y = f2bf(v.y); o.z = f2bf(v.z); o.w = f2bf(v.w);
      ((ushort4*)xb)[i] = o;
    }
    return;
  }

  constexpr int CAP = 1024;
  __shared__ unsigned e_raw[CAP];   // (dc<<26)|(j<<12)|r
  __shared__ float    v_raw[CAP];
  __shared__ uint2    ev_srt[CAP];  // .x = packed meta, .y = float bits
  __shared__ int cnt;
  __shared__ int cstart[65];
  __shared__ int coff[64];
  __shared__ int ccnt[64];
  __shared__ unsigned walsh16[16];  // walsh16[m] bit j = parity(j & m)

  const int tid = threadIdx.x;
  const int ci0 = blockIdx.x * 64;
  const int o0  = (blockIdx.y - 1) * 256;

  if (tid == 0) cnt = 0;
  if (tid < 64) ccnt[tid] = 0;
  if (tid < 16) {
    unsigned m = tid;
    unsigned w = (m & 1 ? 0xAAAAu : 0u) ^ (m & 2 ? 0xCCCCu : 0u)
               ^ (m & 4 ? 0xF0F0u : 0u) ^ (m & 8 ? 0xFF00u : 0u);
    walsh16[m] = w;
  }
  __syncthreads();

  // Phase 1: collect this group's entries
  for (int j = tid; j < NFREQ; j += 256) {
    int c = idx[NFREQ + j];
    if ((c >> 6) == (int)blockIdx.x) {
      int p = atomicAdd(&cnt, 1);
      if (p < CAP) {
        e_raw[p] = ((unsigned)(c & 63) << 26) | ((unsigned)j << 12) | (unsigned)idx[j];
        v_raw[p] = spectrum[j];
        atomicAdd(&ccnt[c & 63], 1);
      }
    }
  }
  __syncthreads();
  const int n = cnt < CAP ? cnt : CAP;

  // Phase 2: prefix sum over 64 column counts (wave 0), then scatter sorted
  if (tid < 64) {
    int v = ccnt[tid];
    int s = v;
    for (int d = 1; d < 64; d <<= 1) {
      int o = __shfl_up(s, d, 64);
      if (tid >= d) s += o;
    }
    cstart[tid + 1] = s;
    if (tid == 0) cstart[0] = 0;
    coff[tid] = s - v;   // exclusive
  }
  __syncthreads();
  for (int e = tid; e < n; e += 256) {
    unsigned w = e_raw[e];
    int dc = w >> 26;
    int p = atomicAdd(&coff[dc], 1);
    ev_srt[p] = make_uint2(w, __float_as_uint(v_raw[e]));
  }
  __syncthreads();

  // Phase 3: last-wins dedup within each column bucket (LDS-local)
  for (int e = tid; e < n; e += 256) {
    uint2 ev = ev_srt[e];
    int dc = ev.x >> 26;
    unsigned r = ev.x & 0xFFFu, j = (ev.x >> 12) & 0x3FFFu;
    int s0 = cstart[dc], e0 = cstart[dc + 1];
    bool dead = false;
    for (int p = s0; p < e0; ++p) {
      unsigned w2 = ev_srt[p].x;
      if ((w2 & 0xFFFu) == r && ((w2 >> 12) & 0x3FFFu) > j) dead = true;
    }
    if (dead) ev_srt[e].y = 0u;   // +0.0f: additive no-op == excluded
  }
  __syncthreads();

  // Phase 4: thread = 4 consecutive cols x 16 CONTIGUOUS rows, entry-outer.
  const int dc0   = (tid & 15) * 4;
  const int rof   = tid >> 4;
  const int obase = o0 + rof * 16;

  float acc[4][16];
#pragma unroll
  for (int c = 0; c < 4; ++c)
#pragma unroll
    for (int j = 0; j < 16; ++j) acc[c][j] = 0.0f;

#pragma unroll
  for (int c = 0; c < 4; ++c) {
    const int s = cstart[dc0 + c], e = cstart[dc0 + c + 1];
    for (int p = s; p < e; ++p) {
      uint2 ev = ev_srt[p];                       // one ds_read_b64 per entry
      unsigned r = ev.x & 0xFFFu;
      unsigned W = walsh16[r & 15u];              // 16-row sign pattern
      unsigned sx = ev.y ^ ((unsigned)(__popc(obase & r) & 1) << 31);  // ±v base sign
#pragma unroll
      for (int j = 0; j < 16; ++j) {
        acc[c][j] += __uint_as_float(sx ^ ((W << (31 - j)) & 0x80000000u));
      }
    }
  }

  // Epilogue: FULL unroll so all acc indices are compile-time (VGPR-resident)
  size_t g = (size_t)obase * K_DIM + ci0 + dc0;
#pragma unroll
  for (int j = 0; j < 16; ++j) {
    float4 w4 = *(const float4*)&weight[g];
    ushort4 ov;
    ov.x = f2bf(w4.x + SCALE * acc[0][j]);
    ov.y = f2bf(w4.y + SCALE * acc[1][j]);
    ov.z = f2bf(w4.z + SCALE * acc[2][j]);
    ov.w = f2bf(w4.w + SCALE * acc[3][j]);
    *(ushort4*)&wb[g] = ov;
    g += K_DIM;
  }
}

// ---------------------------------------------------------------------------
// Kernel 2 (R6): proven R4 gemm_bt (128x128 tile, BK=64, XOR-swizzled LDS,
// global_load_lds 16B, mfma_f32_32x32x16_bf16 2x2, XCD swizzle) + FUSED
// split-K reduction (ticket protocol, removes the reduce_n kernel):
//   both z-halves compute their partial; first to take the tile ticket
//   stores to part + release-flag; second acquire-spins, combines, writes out.
// Deadlock-free: a spinner's partner already passed the ticket atomic.
// R5's coarse pipeline was neutral (m196: coarse phase-split without fine
// interleave captures nothing) -> reverted to best-known inner loop.
// ---------------------------------------------------------------------------
__global__ __launch_bounds__(256) void gemm_bt(
    const ushort_t* __restrict__ A,   // xb [M,K]
    const ushort_t* __restrict__ B,   // wb [N,K]
    float* __restrict__ out,
    float* __restrict__ part,
    int* __restrict__ tickets,
    int* __restrict__ ready,
    int klen) {
  constexpr int BM = 128, BN = 128, BK = 64;
  __shared__ __align__(16) ushort_t As[BM * BK];   // 16 KB
  __shared__ __align__(16) ushort_t Bs[BN * BK];   // 16 KB
  __shared__ int tkt_s;

  const int tid  = threadIdx.x;
  const int wave = tid >> 6, lane = tid & 63;
  const int wrow = wave >> 1, wcol = wave & 1;
  const int l32  = lane & 31, half = lane >> 5;

  // XCD-aware swizzle (bijective on the fixed 32x8 xy-grid)
  const int fid = blockIdx.y * 32 + blockIdx.x;    // 0..255 within z-slice
  const int xcd = fid & 7, w8 = fid >> 3;          // xcd chunk, index in chunk
  const int sx = w8 & 7, sy = w8 >> 3;             // 8x * 4y within chunk
  const int cx = xcd & 3, cy = xcd >> 2;           // chunk grid 4x * 2y
  const int bn = (cx * 8 + sx) * BN;
  const int bm = (cy * 4 + sy) * BM;

  const int kbeg = blockIdx.z * klen;

  const int srow8 = lane >> 3;          // staging: row within chunk, 0..7
  const int sq    = lane & 7;           // 16B slot within row, 0..7

  f32x16_t acc[2][2] = {};

  for (int kt = kbeg; kt < kbeg + klen; kt += BK) {
#pragma unroll
    for (int c = 0; c < 4; ++c) {
      int ch = wave * 4 + c;            // wave-uniform
      int gr = ch * 8 + srow8;          // tile row 0..127
      int qg = sq ^ (gr & 7);           // swizzled source quad
      const ushort_t* ga = A + (size_t)(bm + gr) * K_DIM + kt + qg * 8;
      __builtin_amdgcn_global_load_lds(
          (const __attribute__((address_space(1))) void*)ga,
          (__attribute__((address_space(3))) void*)&As[ch * 512], 16, 0, 0);
      const ushort_t* gb = B + (size_t)(bn + gr) * K_DIM + kt + qg * 8;
      __builtin_amdgcn_global_load_lds(
          (const __attribute__((address_space(1))) void*)gb,
          (__attribute__((address_space(3))) void*)&Bs[ch * 512], 16, 0, 0);
    }
    __syncthreads();

    // fragment loads: frag (mi,h) = A rows [wrow*64+mi*32 .. +32), k half*8+h*16
    bf16x8_t af[2][4], bfr[2][4];
#pragma unroll
    for (int mi = 0; mi < 2; ++mi) {
#pragma unroll
      for (int h = 0; h < 4; ++h) {
        int q = h * 2 + half;           // 16B slot index along k
        int ar = wrow * 64 + mi * 32 + l32;
        af[mi][h]  = *(const bf16x8_t*)&As[ar * BK + ((q ^ (ar & 7)) * 8)];
        int br = wcol * 64 + mi * 32 + l32;
        bfr[mi][h] = *(const bf16x8_t*)&Bs[br * BK + ((q ^ (br & 7)) * 8)];
      }
    }
#pragma unroll
    for (int h = 0; h < 4; ++h)
#pragma unroll
      for (int mi = 0; mi < 2; ++mi)
#pragma unroll
        for (int nj = 0; nj < 2; ++nj)
          acc[mi][nj] = __builtin_amdgcn_mfma_f32_32x32x16_bf16(
              af[mi][h], bfr[nj][h], acc[mi][nj], 0, 0, 0);
    __syncthreads();
  }

  // ---- fused split-K epilogue ----
  // C/D layout: col = lane&31, row = (reg&3) + 8*(reg>>2) + 4*half (verified)
  if (gridDim.z == 1) {
#pragma unroll
    for (int mi = 0; mi < 2; ++mi)
#pragma unroll
      for (int nj = 0; nj < 2; ++nj) {
        int col  = bn + wcol * 64 + nj * 32 + l32;
        int rwb  = bm + wrow * 64 + mi * 32 + 4 * half;
#pragma unroll
        for (int reg = 0; reg < 16; ++reg) {
          int row = rwb + (reg & 3) + 8 * (reg >> 2);
          out[(size_t)row * N_DIM + col] = acc[mi][nj][reg];
        }
      }
    return;
  }

  if (tid == 0) tkt_s = atomicAdd(&tickets[fid], 1);
  __syncthreads();
  const bool first = (tkt_s == 0);

  if (first) {
    // store partial, then publish
#pragma unroll
    for (int mi = 0; mi < 2; ++mi)
#pragma unroll
      for (int nj = 0; nj < 2; ++nj) {
        int col  = bn + wcol * 64 + nj * 32 + l32;
        int rwb  = bm + wrow * 64 + mi * 32 + 4 * half;
#pragma unroll
        for (int reg = 0; reg < 16; ++reg) {
          int row = rwb + (reg & 3) + 8 * (reg >> 2);
          part[(size_t)row * N_DIM + col] = acc[mi][nj][reg];
        }
      }
    __threadfence();       // drain + make stores agent-visible
    __syncthreads();       // all threads' stores fenced
    if (tid == 0)
      __hip_atomic_store(&ready[fid], 1, __ATOMIC_RELEASE,
                         __HIP_MEMORY_SCOPE_AGENT);
  } else {
    if (tid == 0) {
      while (__hip_atomic_load(&ready[fid], __ATOMIC_ACQUIRE,
                               __HIP_MEMORY_SCOPE_AGENT) == 0)
        __builtin_amdgcn_s_sleep(1);
    }
    __syncthreads();       // all threads ordered after the acquire
#pragma unroll
    for (int mi = 0; mi < 2; ++mi)
#pragma unroll
      for (int nj = 0; nj < 2; ++nj) {
        int col  = bn + wcol * 64 + nj * 32 + l32;
        int rwb  = bm + wrow * 64 + mi * 32 + 4 * half;
#pragma unroll
        for (int reg = 0; reg < 16; ++reg) {
          int row = rwb + (reg & 3) + 8 * (reg >> 2);
          size_t o = (size_t)row * N_DIM + col;
          out[o] = part[o] + acc[mi][nj][reg];
        }
      }
  }
}

extern "C" void kernel_launch(void* const* d_in, const int* in_sizes, int n_in,
                              void* d_out, int out_size, void* d_ws, size_t ws_size,
                              hipStream_t stream) {
  const float* x        = (const float*)d_in[0];   // [2,512,4096]
  const float* weight   = (const float*)d_in[1];   // [4096,4096]
  const float* spectrum = (const float*)d_in[2];   // [10000]
  const int*   indices  = (const int*)d_in[3];     // [2,10000]
  float* out = (float*)d_out;                      // [2,512,4096]

  char* ws = (char*)d_ws;
  const size_t WB_BYTES = (size_t)N_DIM * K_DIM * 2;   // 32 MB
  const size_t XB_BYTES = (size_t)M_DIM * K_DIM * 2;   //  8 MB
  const size_t P1_BYTES = (size_t)M_DIM * N_DIM * 4;   // 16 MB partial
  const size_t FLAG_BYTES = 2 * 256 * sizeof(int);

  ushort_t* wb = (ushort_t*)ws;
  ushort_t* xb = (ushort_t*)(ws + WB_BYTES);
  float* part  = (float*)(ws + WB_BYTES + XB_BYTES);
  int* tickets = (int*)(ws + WB_BYTES + XB_BYTES + P1_BYTES);
  int* ready   = tickets + 256;

  int zsplit =
      (ws_size >= WB_BYTES + XB_BYTES + P1_BYTES + FLAG_BYTES) ? 2 : 1;

  // convert x + zero flags (y=0, dispatched first) + build W' (y=1..16)
  build_w4<<<dim3(64, 17), 256, 0, stream>>>(weight, spectrum, indices, x,
                                             wb, xb, tickets, ready);

  // 32 x 8 x 2 = 512 blocks; split-K reduction fused via ticket protocol
  gemm_bt<<<dim3(N_DIM / 128, M_DIM / 128, zsplit), 256, 0, stream>>>(
      xb, wb, out, part, tickets, ready, K_DIM / zsplit);
}

// Round 7
// 185.552 us; speedup vs baseline: 1.1980x; 1.1980x over previous
//
#include <hip/hip_runtime.h>

typedef unsigned short ushort_t;

#define M_DIM 1024   // 2*512 rows of x
#define N_DIM 4096   // OUT_F
#define K_DIM 4096   // IN_F
#define NFREQ 10000
constexpr float SCALE = 150.0f / 64.0f;   // 150 / sqrt(4096)

typedef __bf16 bf16x8_t  __attribute__((ext_vector_type(8)));
typedef float  f32x16_t  __attribute__((ext_vector_type(16)));

// Native RNE f32->bf16 (R4: measured -2us steady vs bit-twiddle RNE)
__device__ inline ushort_t f2bf(float f) {
  union { __bf16 h; ushort_t u; } v;
  v.h = (__bf16)f;
  return v.u;
}

// ---------------------------------------------------------------------------
// Kernel 1: W' = bf16( weight + s * iwht(scatter(spectrum,idx)) ), plus
// x fp32->bf16 folded in as grid-y slice 0.
// R7 change: 4-deep rotating prefetch in the W-epilogue. R2's 16-deep failed
// via VGPR 80 (occupancy 34->21%); occupancy here is GRID-limited (~17
// waves/CU ceiling at 64x17 blocks), and VGPR only binds at the 64/128
// quanta -> +4 float4 (~68 VGPR) keeps >=4 waves/SIMD while holding 4 loads
// in flight instead of ~1-2 (epilogue was latency-bound at ~1.7 TB/s).
// Everything fully unrolled: all wv/ov/acc indices compile-time.
// ---------------------------------------------------------------------------
__global__ __launch_bounds__(256) void build_w4(
    const float* __restrict__ weight,
    const float* __restrict__ spectrum,
    const int* __restrict__ idx,          // [2][NFREQ]: row 0 = r (out), row 1 = c (in)
    const float* __restrict__ x,
    ushort_t* __restrict__ wb,
    ushort_t* __restrict__ xb) {
  // ---- folded cvt_x slice (dispatched first) ----
  if (blockIdx.y == 0) {
    int flat = blockIdx.x * 256 + threadIdx.x;    // 16384 threads
#pragma unroll 4
    for (int k = 0; k < 64; ++k) {
      int i = flat + k * 16384;                   // M*K/4 = 1048576 float4s
      float4 v = ((const float4*)x)[i];
      ushort4 o;
      o.x = f2bf(v.x); o.y = f2bf(v.y); o.z = f2bf(v.z); o.w = f2bf(v.w);
      ((ushort4*)xb)[i] = o;
    }
    return;
  }

  constexpr int CAP = 1024;
  __shared__ unsigned e_raw[CAP];   // (dc<<26)|(j<<12)|r
  __shared__ float    v_raw[CAP];
  __shared__ uint2    ev_srt[CAP];  // .x = packed meta, .y = float bits
  __shared__ int cnt;
  __shared__ int cstart[65];
  __shared__ int coff[64];
  __shared__ int ccnt[64];
  __shared__ unsigned walsh16[16];  // walsh16[m] bit j = parity(j & m)

  const int tid = threadIdx.x;
  const int ci0 = blockIdx.x * 64;
  const int o0  = (blockIdx.y - 1) * 256;

  if (tid == 0) cnt = 0;
  if (tid < 64) ccnt[tid] = 0;
  if (tid < 16) {
    unsigned m = tid;
    unsigned w = (m & 1 ? 0xAAAAu : 0u) ^ (m & 2 ? 0xCCCCu : 0u)
               ^ (m & 4 ? 0xF0F0u : 0u) ^ (m & 8 ? 0xFF00u : 0u);
    walsh16[m] = w;
  }
  __syncthreads();

  // Phase 1: collect this group's entries
  for (int j = tid; j < NFREQ; j += 256) {
    int c = idx[NFREQ + j];
    if ((c >> 6) == (int)blockIdx.x) {
      int p = atomicAdd(&cnt, 1);
      if (p < CAP) {
        e_raw[p] = ((unsigned)(c & 63) << 26) | ((unsigned)j << 12) | (unsigned)idx[j];
        v_raw[p] = spectrum[j];
        atomicAdd(&ccnt[c & 63], 1);
      }
    }
  }
  __syncthreads();
  const int n = cnt < CAP ? cnt : CAP;

  // Phase 2: prefix sum over 64 column counts (wave 0), then scatter sorted
  if (tid < 64) {
    int v = ccnt[tid];
    int s = v;
    for (int d = 1; d < 64; d <<= 1) {
      int o = __shfl_up(s, d, 64);
      if (tid >= d) s += o;
    }
    cstart[tid + 1] = s;
    if (tid == 0) cstart[0] = 0;
    coff[tid] = s - v;   // exclusive
  }
  __syncthreads();
  for (int e = tid; e < n; e += 256) {
    unsigned w = e_raw[e];
    int dc = w >> 26;
    int p = atomicAdd(&coff[dc], 1);
    ev_srt[p] = make_uint2(w, __float_as_uint(v_raw[e]));
  }
  __syncthreads();

  // Phase 3: last-wins dedup within each column bucket (LDS-local)
  for (int e = tid; e < n; e += 256) {
    uint2 ev = ev_srt[e];
    int dc = ev.x >> 26;
    unsigned r = ev.x & 0xFFFu, j = (ev.x >> 12) & 0x3FFFu;
    int s0 = cstart[dc], e0 = cstart[dc + 1];
    bool dead = false;
    for (int p = s0; p < e0; ++p) {
      unsigned w2 = ev_srt[p].x;
      if ((w2 & 0xFFFu) == r && ((w2 >> 12) & 0x3FFFu) > j) dead = true;
    }
    if (dead) ev_srt[e].y = 0u;   // +0.0f: additive no-op == excluded
  }
  __syncthreads();

  // Phase 4: thread = 4 consecutive cols x 16 CONTIGUOUS rows, entry-outer.
  const int dc0   = (tid & 15) * 4;
  const int rof   = tid >> 4;
  const int obase = o0 + rof * 16;

  float acc[4][16];
#pragma unroll
  for (int c = 0; c < 4; ++c)
#pragma unroll
    for (int j = 0; j < 16; ++j) acc[c][j] = 0.0f;

#pragma unroll
  for (int c = 0; c < 4; ++c) {
    const int s = cstart[dc0 + c], e = cstart[dc0 + c + 1];
    for (int p = s; p < e; ++p) {
      uint2 ev = ev_srt[p];                       // one ds_read_b64 per entry
      unsigned r = ev.x & 0xFFFu;
      unsigned W = walsh16[r & 15u];              // 16-row sign pattern
      unsigned sx = ev.y ^ ((unsigned)(__popc(obase & r) & 1) << 31);  // ±v base sign
#pragma unroll
      for (int j = 0; j < 16; ++j) {
        acc[c][j] += __uint_as_float(sx ^ ((W << (31 - j)) & 0x80000000u));
      }
    }
  }

  // Epilogue: 4-deep rotating prefetch, FULL unroll (compile-time indices).
  // Per group of 4 rows: compute ov from resident wv -> issue NEXT 4 loads
  // -> issue 4 stores. Keeps 4 loads in flight under the cvt/store work.
  const size_t gaddr = (size_t)obase * K_DIM + ci0 + dc0;
  float4 wv[4];
#pragma unroll
  for (int u = 0; u < 4; ++u)
    wv[u] = *(const float4*)&weight[gaddr + (size_t)u * K_DIM];

#pragma unroll
  for (int jb = 0; jb < 4; ++jb) {
    ushort4 ov[4];
#pragma unroll
    for (int u = 0; u < 4; ++u) {
      const int j = jb * 4 + u;
      ov[u].x = f2bf(wv[u].x + SCALE * acc[0][j]);
      ov[u].y = f2bf(wv[u].y + SCALE * acc[1][j]);
      ov[u].z = f2bf(wv[u].z + SCALE * acc[2][j]);
      ov[u].w = f2bf(wv[u].w + SCALE * acc[3][j]);
    }
    if (jb < 3) {
#pragma unroll
      for (int u = 0; u < 4; ++u)
        wv[u] = *(const float4*)&weight[gaddr + (size_t)(jb * 4 + 4 + u) * K_DIM];
    }
#pragma unroll
    for (int u = 0; u < 4; ++u)
      *(ushort4*)&wb[gaddr + (size_t)(jb * 4 + u) * K_DIM] = ov[u];
  }
}

// ---------------------------------------------------------------------------
// Kernel 2: C[M,N] = A[M,K] * B[N,K]^T  (bf16 in, fp32 out), split-K via z.
// R4-exact (best known: ~47us, VGPR 60). 128x128 tile, BK=64, XOR-swizzled
// LDS, global_load_lds 16B staging, mfma_f32_32x32x16_bf16 2x2, XCD swizzle.
// R6's fused split-K reduction REVERTED: ticket spin + epilogue bloat drove
// VGPR 60->112 and dur 47->96us. Separate reduce_n is strictly better.
// ---------------------------------------------------------------------------
__global__ __launch_bounds__(256) void gemm_bt(
    const ushort_t* __restrict__ A,   // xb [M,K]
    const ushort_t* __restrict__ B,   // wb [N,K]
    float* __restrict__ C0,
    float* __restrict__ C1,
    int klen) {
  constexpr int BM = 128, BN = 128, BK = 64;
  __shared__ __align__(16) ushort_t As[BM * BK];   // 16 KB
  __shared__ __align__(16) ushort_t Bs[BN * BK];   // 16 KB

  const int tid  = threadIdx.x;
  const int wave = tid >> 6, lane = tid & 63;
  const int wrow = wave >> 1, wcol = wave & 1;
  const int l32  = lane & 31, half = lane >> 5;

  // XCD-aware swizzle (bijective on the fixed 32x8 xy-grid)
  const int fid = blockIdx.y * 32 + blockIdx.x;    // 0..255 within z-slice
  const int xcd = fid & 7, w8 = fid >> 3;          // xcd chunk, index in chunk
  const int sx = w8 & 7, sy = w8 >> 3;             // 8x * 4y within chunk
  const int cx = xcd & 3, cy = xcd >> 2;           // chunk grid 4x * 2y
  const int bn = (cx * 8 + sx) * BN;
  const int bm = (cy * 4 + sy) * BM;

  const int kbeg = blockIdx.z * klen;
  float* __restrict__ dst = blockIdx.z == 0
      ? C0 : C1 + (size_t)(blockIdx.z - 1) * M_DIM * N_DIM;

  const int srow8 = lane >> 3;          // staging: row within chunk, 0..7
  const int sq    = lane & 7;           // 16B slot within row, 0..7

  f32x16_t acc[2][2] = {};

  for (int kt = kbeg; kt < kbeg + klen; kt += BK) {
#pragma unroll
    for (int c = 0; c < 4; ++c) {
      int ch = wave * 4 + c;            // wave-uniform
      int gr = ch * 8 + srow8;          // tile row 0..127
      int qg = sq ^ (gr & 7);           // swizzled source quad
      const ushort_t* ga = A + (size_t)(bm + gr) * K_DIM + kt + qg * 8;
      __builtin_amdgcn_global_load_lds(
          (const __attribute__((address_space(1))) void*)ga,
          (__attribute__((address_space(3))) void*)&As[ch * 512], 16, 0, 0);
      const ushort_t* gb = B + (size_t)(bn + gr) * K_DIM + kt + qg * 8;
      __builtin_amdgcn_global_load_lds(
          (const __attribute__((address_space(1))) void*)gb,
          (__attribute__((address_space(3))) void*)&Bs[ch * 512], 16, 0, 0);
    }
    __syncthreads();

    // fragment loads: frag (mi,h) = A rows [wrow*64+mi*32 .. +32), k half*8+h*16
    bf16x8_t af[2][4], bfr[2][4];
#pragma unroll
    for (int mi = 0; mi < 2; ++mi) {
#pragma unroll
      for (int h = 0; h < 4; ++h) {
        int q = h * 2 + half;           // 16B slot index along k
        int ar = wrow * 64 + mi * 32 + l32;
        af[mi][h]  = *(const bf16x8_t*)&As[ar * BK + ((q ^ (ar & 7)) * 8)];
        int br = wcol * 64 + mi * 32 + l32;
        bfr[mi][h] = *(const bf16x8_t*)&Bs[br * BK + ((q ^ (br & 7)) * 8)];
      }
    }
#pragma unroll
    for (int h = 0; h < 4; ++h)
#pragma unroll
      for (int mi = 0; mi < 2; ++mi)
#pragma unroll
        for (int nj = 0; nj < 2; ++nj)
          acc[mi][nj] = __builtin_amdgcn_mfma_f32_32x32x16_bf16(
              af[mi][h], bfr[nj][h], acc[mi][nj], 0, 0, 0);
    __syncthreads();
  }

  // epilogue: col = lane&31, row = (reg&3) + 8*(reg>>2) + 4*half
#pragma unroll
  for (int mi = 0; mi < 2; ++mi) {
#pragma unroll
    for (int nj = 0; nj < 2; ++nj) {
      int col  = bn + wcol * 64 + nj * 32 + l32;
      int rwb  = bm + wrow * 64 + mi * 32 + 4 * half;
#pragma unroll
      for (int reg = 0; reg < 16; ++reg) {
        int row = rwb + (reg & 3) + 8 * (reg >> 2);
        dst[(size_t)row * N_DIM + col] = acc[mi][nj][reg];
      }
    }
  }
}

// ---------------------------------------------------------------------------
// Kernel 3: out += sum of npart partial arrays (float4)
// ---------------------------------------------------------------------------
__global__ __launch_bounds__(256) void reduce_n(float* __restrict__ out,
                                                const float* __restrict__ part,
                                                int npart) {
  int i = blockIdx.x * 256 + threadIdx.x;
  float4 a = ((const float4*)out)[i];
  for (int t = 0; t < npart; ++t) {
    float4 b = ((const float4*)(part + (size_t)t * M_DIM * N_DIM))[i];
    a.x += b.x; a.y += b.y; a.z += b.z; a.w += b.w;
  }
  ((float4*)out)[i] = a;
}

extern "C" void kernel_launch(void* const* d_in, const int* in_sizes, int n_in,
                              void* d_out, int out_size, void* d_ws, size_t ws_size,
                              hipStream_t stream) {
  const float* x        = (const float*)d_in[0];   // [2,512,4096]
  const float* weight   = (const float*)d_in[1];   // [4096,4096]
  const float* spectrum = (const float*)d_in[2];   // [10000]
  const int*   indices  = (const int*)d_in[3];     // [2,10000]
  float* out = (float*)d_out;                      // [2,512,4096]

  char* ws = (char*)d_ws;
  const size_t WB_BYTES = (size_t)N_DIM * K_DIM * 2;   // 32 MB
  const size_t XB_BYTES = (size_t)M_DIM * K_DIM * 2;   //  8 MB
  const size_t P1_BYTES = (size_t)M_DIM * N_DIM * 4;   // 16 MB per partial

  ushort_t* wb = (ushort_t*)ws;
  ushort_t* xb = (ushort_t*)(ws + WB_BYTES);
  float* part = (float*)(ws + WB_BYTES + XB_BYTES);

  // zsplit=2 measured best (R1: zsplit=4 gemm 48+13; R6: fused 96)
  int zsplit = (ws_size >= WB_BYTES + XB_BYTES + P1_BYTES) ? 2 : 1;

  // convert x (y=0, dispatched first) + build W' (y=1..16) in one dispatch
  build_w4<<<dim3(64, 17), 256, 0, stream>>>(weight, spectrum, indices, x, wb, xb);

  gemm_bt<<<dim3(N_DIM / 128, M_DIM / 128, zsplit), 256, 0, stream>>>(
      xb, wb, out, part, K_DIM / zsplit);
  if (zsplit > 1)
    reduce_n<<<(M_DIM * N_DIM / 4) / 256, 256, 0, stream>>>(out, part, zsplit - 1);
}